// Round 1
// baseline (629.707 us; speedup 1.0000x reference)
//
#include <hip/hip_runtime.h>

// Shifted 3x3 VALID conv: out[n][o][x][y] = bias[o] +
//   sum_{c,i,j} inp[n][c][wrap(x+i-1)][y+j] * filt[o][c][i][j]
// B=8, Cin=Cout=8, H=W=1024, OH=OW=1022, fp32.
//
// R3: no-LDS direct-global version. R2 was issue-stalled (VALUBusy 52%,
// HBM 34%, occupancy 76%): single-buffered stage->vmcnt(0)->barrier->compute
// drained all 8 waves per block, and staging addressing (div-by-17 magic,
// LDS writes) bought nothing since there is no cross-channel reuse - the
// 3x(j) / 3x(row) overlap is L1-resident. Here each thread reads its own
// 4-row x 3-col window per channel straight from global (coalesced
// dwordx3 per lane), row wrap/clamp folded into 4 pointers computed once,
// c-loop register-double-buffered so c+1 loads hide under c's 144 FMAs.
// No barrier, no LDS; occupancy is VGPR-bound (~7-8 waves/SIMD).

#define H     1024
#define W     1024
#define OH    1022
#define OW    1022
#define CIN   8
#define COUT  8

#define TY    64            // output cols per block (= lanes per wave)
#define NTG   4             // waves per block
#define RPT   2             // output rows per thread
#define TX    (NTG * RPT)   // 8 output rows per block
#define NTHREADS (TY * NTG) // 256
#define NROWS (RPT + 2)     // 4 input rows per thread window

__global__ __launch_bounds__(NTHREADS, 6)
void conv_roll_kernel(const float* __restrict__ inp,
                      const float* __restrict__ filt,
                      const float* __restrict__ bias,
                      float* __restrict__ out) {
    const int tid = threadIdx.x;
    const int ty  = tid & 63;      // lane -> output column within tile
    const int tg  = tid >> 6;      // wave -> row group
    const int n      = blockIdx.z;
    const int x_base = blockIdx.y * TX;
    const int y_base = blockIdx.x * TY;

    const int yc  = y_base + ty;
    // Loads touch cols [ycl, ycl+2]; clamp so dead lanes (yc >= OW) stay in-bounds.
    const int ycl = (yc > W - 3) ? (W - 3) : yc;

    const int xr0 = x_base + tg * RPT;   // first output row of this thread

    // Row pointers for input rows xr0-1 .. xr0+RPT, with roll-wrap at -1 and
    // clamp at the bottom (clamped rows only feed store-guarded dead outputs).
    const float* rp[NROWS];
#pragma unroll
    for (int rr = 0; rr < NROWS; ++rr) {
        int r = xr0 + rr - 1;
        r = (r < 0) ? (H - 1) : ((r > H - 1) ? (H - 1) : r);
        rp[rr] = inp + ((size_t)n * CIN * H + r) * W + ycl;
    }

    float acc[RPT][COUT];
#pragma unroll
    for (int o = 0; o < COUT; ++o) {
        const float bv = bias[o];                    // uniform -> s_load
#pragma unroll
        for (int u = 0; u < RPT; ++u) acc[u][o] = bv;
    }

    float A[NROWS][3], B[NROWS][3];

    auto loadrows = [&](float (&buf)[NROWS][3]) {
#pragma unroll
        for (int rr = 0; rr < NROWS; ++rr)
#pragma unroll
            for (int j = 0; j < 3; ++j)
                buf[rr][j] = rp[rr][j];              // per-lane 12B -> dwordx3, coalesced
    };
    auto adv = [&]() {
#pragma unroll
        for (int rr = 0; rr < NROWS; ++rr) rp[rr] += (size_t)H * W;
    };
    auto compute = [&](const float (&buf)[NROWS][3], int c) {
#pragma unroll
        for (int i = 0; i < 3; ++i)
#pragma unroll
            for (int j = 0; j < 3; ++j)
#pragma unroll
                for (int o = 0; o < COUT; ++o) {
                    const float fv = filt[((o * CIN + c) * 3 + i) * 3 + j];  // uniform -> s_load
#pragma unroll
                    for (int u = 0; u < RPT; ++u)
                        acc[u][o] += buf[u + i][j] * fv;
                }
    };

    // Register-double-buffered channel loop: loads for c+1 in flight under
    // the 144 FMAs of c. All buffer indices compile-time (no scratch).
    loadrows(A);        // c = 0
    adv();              // rp -> c = 1
#pragma unroll 1
    for (int c = 0; c < CIN - 2; c += 2) {
        loadrows(B);    // c + 1
        adv();
        compute(A, c);
        loadrows(A);    // c + 2
        adv();
        compute(B, c + 1);
    }
    // Tail: c = 6,7 (no pointer advance past the last plane -> no OOB reads)
    loadrows(B);        // c = 7
    compute(A, CIN - 2);
    compute(B, CIN - 1);

    // ---- Store (coalesced across lanes) ----
    if (yc < OW) {
#pragma unroll
        for (int u = 0; u < RPT; ++u) {
            const int xr = xr0 + u;
            if (xr < OH) {
#pragma unroll
                for (int o = 0; o < COUT; ++o)
                    out[(((size_t)(n * COUT + o)) * OH + xr) * OW + yc] = acc[u][o];
            }
        }
    }
}

extern "C" void kernel_launch(void* const* d_in, const int* in_sizes, int n_in,
                              void* d_out, int out_size, void* d_ws, size_t ws_size,
                              hipStream_t stream) {
    const float* inp  = (const float*)d_in[0];
    const float* filt = (const float*)d_in[1];
    const float* bias = (const float*)d_in[2];
    float* out = (float*)d_out;

    dim3 grid((OW + TY - 1) / TY,   // 16 y-tiles
              (OH + TX - 1) / TX,   // 128 x-tiles
              8);                   // batch
    conv_roll_kernel<<<grid, dim3(NTHREADS), 0, stream>>>(inp, filt, bias, out);
}